// Round 16
// baseline (947.113 us; speedup 1.0000x reference)
//
#include <hip/hip_runtime.h>
#include <hip/hip_bf16.h>
#include <cstdint>
#include <cstddef>

#define DI __device__ __forceinline__

typedef __bf16 bf16_t;
typedef bf16_t bf16x8 __attribute__((ext_vector_type(8)));
typedef float f32x4 __attribute__((ext_vector_type(4)));

constexpr int Vn = 4, Bn = 2, Hn = 32, Wn = 64, Zn = 13, Cn = 256, HIDn = 1024;
constexpr int Ln = Hn * Wn * Zn;                 // 26624
constexpr int BWn = Bn * (Hn / 4) * (Wn / 4) * Zn; // 3328 windows (B_)
constexpr int PB = Bn * Ln;                      // 53248 rows per variable
constexpr int ROWS = Vn * PB;                    // 212992

// ---------- global -> LDS direct staging (16B per lane; LDS dest wave-uniform) ----------
DI void gload_lds16(const void* g, void* l) {
  __builtin_amdgcn_global_load_lds(
      (const __attribute__((address_space(1))) void*)g,
      (__attribute__((address_space(3))) void*)l, 16, 0, 0);
}

DI unsigned short f2bf_bits(float f) {
  __hip_bfloat16 h = __float2bfloat16(f);
  return *reinterpret_cast<unsigned short*>(&h);
}

DI float gelu_f(float x) {
  // sigmoid-form tanh-GELU with v_rcp_f32 (no IEEE divide)
  float u = x * x;
  float w = x * fmaf(0.044715f, u, 1.0f);
  float e = __expf(-1.5957691216057308f * w);
  return x * __builtin_amdgcn_rcpf(1.0f + e);
}

// ---------- tiled weight transpose: src [V][K][N] f32 -> dst [V][N][K] bf16 ----------
__global__ __launch_bounds__(256) void transpose_tile_kernel(
    const float* __restrict__ src, __hip_bfloat16* __restrict__ dst, int K, int N) {
  __shared__ float S[64][65];
  const int n0 = blockIdx.x * 64, k0 = blockIdx.y * 64, v = blockIdx.z;
  const int tc = threadIdx.x & 63, tr = threadIdx.x >> 6;  // tr 0..3
#pragma unroll
  for (int i = 0; i < 16; ++i) {
    int kk = tr + i * 4;
    S[kk][tc] = src[((size_t)v * K + k0 + kk) * N + n0 + tc];
  }
  __syncthreads();
#pragma unroll
  for (int i = 0; i < 16; ++i) {
    int nn = tr + i * 4;
    dst[((size_t)v * N + n0 + nn) * K + k0 + tc] = __float2bfloat16(S[tc][nn]);
  }
}

// ---------- LN1 fused with cyclic shift + window partition ----------
__global__ __launch_bounds__(256) void ln1_kernel(
    const float* __restrict__ x0, const float* __restrict__ x1,
    const float* __restrict__ x2i, const float* __restrict__ x3,
    const float* __restrict__ g_, const float* __restrict__ b_,
    __hip_bfloat16* __restrict__ xw) {
  int gw = blockIdx.x * 4 + (threadIdx.x >> 6);
  int lane = threadIdx.x & 63;
  int v = gw / PB;
  int rem = gw - v * PB;
  int bw = rem >> 4, nn = rem & 15;
  int zb = bw % 13;
  int t = bw / 13;
  int wb = t & 15, t2 = t >> 4;
  int hb = t2 & 7, b = t2 >> 3;
  int hs = (hb * 4 + (nn >> 2) + 30) & 31;   // (h - 2) mod 32
  int wsrc = (wb * 4 + (nn & 3) + 62) & 63;  // (w - 2) mod 64
  size_t l = (size_t)(hs * 64 + wsrc) * 13 + zb;
  const float* xv = (v == 0) ? x0 : (v == 1) ? x1 : (v == 2) ? x2i : x3;
  const float* xp = xv + ((size_t)b * Ln + l) * 256;
  float4 val = *(const float4*)(xp + lane * 4);
  float s = val.x + val.y + val.z + val.w;
  float sq = val.x * val.x + val.y * val.y + val.z * val.z + val.w * val.w;
#pragma unroll
  for (int o = 32; o; o >>= 1) {
    s += __shfl_xor(s, o);
    sq += __shfl_xor(sq, o);
  }
  float mean = s * (1.0f / 256.0f);
  float var = sq * (1.0f / 256.0f) - mean * mean;
  float rstd = rsqrtf(var + 1e-5f);
  const float* gg = g_ + v * 256 + lane * 4;
  const float* bb = b_ + v * 256 + lane * 4;
  ushort4 o4;
  o4.x = f2bf_bits((val.x - mean) * rstd * gg[0] + bb[0]);
  o4.y = f2bf_bits((val.y - mean) * rstd * gg[1] + bb[1]);
  o4.z = f2bf_bits((val.z - mean) * rstd * gg[2] + bb[2]);
  o4.w = f2bf_bits((val.w - mean) * rstd * gg[3] + bb[3]);
  *reinterpret_cast<ushort4*>(xw + (size_t)gw * 256 + lane * 4) = o4;
}

// ---------- windowed attention (verified) ----------
__global__ __launch_bounds__(256) void attn_kernel(
    const __hip_bfloat16* __restrict__ qkvp, __hip_bfloat16* __restrict__ ctx) {
  __shared__ float P[4][16][17];
  int b_ = blockIdx.x;
  int v = blockIdx.y;
  int wid = threadIdx.x >> 6, lane = threadIdx.x & 63;
  int lm = lane & 15, hi = lane >> 4;
  const bf16_t* base = (const bf16_t*)qkvp + (size_t)(v * BWn + b_) * 16 * 768;
  const float scale = 0.17677669529663687f;  // 32^-0.5
  f32x4 zero = {0.f, 0.f, 0.f, 0.f};
#pragma unroll
  for (int hh = 0; hh < 2; ++hh) {
    int h = wid + 4 * hh;
    bf16x8 qf = *(const bf16x8*)(base + (size_t)lm * 768 + h * 32 + hi * 8);
    bf16x8 kf = *(const bf16x8*)(base + (size_t)lm * 768 + 256 + h * 32 + hi * 8);
    f32x4 s = __builtin_amdgcn_mfma_f32_16x16x32_bf16(qf, kf, zero, 0, 0, 0);
    float p0[4];
#pragma unroll
    for (int q = 0; q < 4; ++q) {
      float val = s[q] * scale;
      float mx = val;
#pragma unroll
      for (int o = 8; o >= 1; o >>= 1) mx = fmaxf(mx, __shfl_xor(mx, o));
      float e = __expf(val - mx);
      float sum = e;
#pragma unroll
      for (int o = 8; o >= 1; o >>= 1) sum += __shfl_xor(sum, o);
      p0[q] = e * __builtin_amdgcn_rcpf(sum);
    }
#pragma unroll
    for (int q = 0; q < 4; ++q) P[wid][hi * 4 + q][lm] = p0[q];
    bf16x8 pa;
#pragma unroll
    for (int j = 0; j < 8; ++j) pa[j] = (bf16_t)0.f;
    if (hi < 2) {
#pragma unroll
      for (int j = 0; j < 8; ++j) pa[j] = (bf16_t)P[wid][lm][hi * 8 + j];
    }
#pragma unroll
    for (int dh = 0; dh < 2; ++dh) {
      bf16x8 vf;
#pragma unroll
      for (int j = 0; j < 8; ++j) vf[j] = (bf16_t)0.f;
      if (hi < 2) {
#pragma unroll
        for (int j = 0; j < 8; ++j)
          vf[j] = base[(size_t)(hi * 8 + j) * 768 + 512 + h * 32 + dh * 16 + lm];
      }
      f32x4 c = __builtin_amdgcn_mfma_f32_16x16x32_bf16(pa, vf, zero, 0, 0, 0);
#pragma unroll
      for (int q = 0; q < 4; ++q) {
        int n = hi * 4 + q;
        int d = dh * 16 + lm;
        int r = n * 4 + v;
        int vo = r >> 4, no = r & 15;
        ctx[((size_t)(vo * BWn + b_) * 16 + no) * 256 + h * 32 + d] = __float2bfloat16(c[q]);
      }
    }
  }
}

// ---------- GEMM v4 (verified): 128x128 tile, 4 waves, BK=64, 40KB LDS -> 3 blocks/CU ----------
// EPI: 0 = qkv (bias, bf16), 1 = proj (bias + window-reverse + roll + shortcut -> f32 x2)
template <int EPI, int K, int N>
__global__ __launch_bounds__(256, 3) void gemm4(
    const __hip_bfloat16* __restrict__ A, const __hip_bfloat16* __restrict__ WT,
    const float* __restrict__ bias, __hip_bfloat16* __restrict__ outb,
    float* __restrict__ outf, const float* __restrict__ xi0,
    const float* __restrict__ xi1, const float* __restrict__ xi2,
    const float* __restrict__ xi3) {
  constexpr int NT = K / 64;
  constexpr int NC = N / 128;
  const int v = blockIdx.z;
  const int x = blockIdx.x;
  const int xcd = x & 7;
  const int j = x >> 3;
  const int c = j % NC;
  const int r = xcd + 8 * (j / NC);
  const int rowBase = r * 128;
  const int colBase = c * 128;

  const bf16_t* Av = (const bf16_t*)A + ((size_t)v * PB + rowBase) * K;
  const bf16_t* Wv = (const bf16_t*)WT + ((size_t)v * N + colBase) * K;

  __shared__ __align__(16) uint8_t smem[40960];
  bf16_t(*As)[64] = (bf16_t(*)[64])smem;             // [128][64]
  bf16_t(*Bs)[64] = (bf16_t(*)[64])(smem + 16384);   // [128][64]

  const int tid = threadIdx.x, wid = tid >> 6, lane = tid & 63;
  const int wr = wid >> 1, wc = wid & 1;
  const int lm = lane & 15, hi = lane >> 4;
  const int rA = lane >> 3;
  const int lg = (lane & 7) ^ rA;

  f32x4 acc[4][4];
#pragma unroll
  for (int m = 0; m < 4; ++m)
#pragma unroll
    for (int n = 0; n < 4; ++n) acc[m][n] = f32x4{0.f, 0.f, 0.f, 0.f};

  for (int t = 0; t < NT; ++t) {
    if (t) __syncthreads();
#pragma unroll
    for (int g = 0; g < 4; ++g) {
      int grp = wid * 4 + g;
      gload_lds16(Av + (size_t)(grp * 8 + rA) * K + t * 64 + lg * 8, &As[grp * 8][0]);
    }
#pragma unroll
    for (int g = 0; g < 4; ++g) {
      int grp = wid * 4 + g;
      gload_lds16(Wv + (size_t)(grp * 8 + rA) * K + t * 64 + lg * 8, &Bs[grp * 8][0]);
    }
    __syncthreads();
#pragma unroll
    for (int kk = 0; kk < 2; ++kk) {
      bf16x8 af[4], bfv[4];
#pragma unroll
      for (int m = 0; m < 4; ++m) {
        const int rr = wr * 64 + m * 16 + lm;
        af[m] = *(const bf16x8*)&As[rr][((kk * 4 + hi) ^ (lm & 7)) * 8];
      }
#pragma unroll
      for (int n = 0; n < 4; ++n) {
        const int rr = wc * 64 + n * 16 + lm;
        bfv[n] = *(const bf16x8*)&Bs[rr][((kk * 4 + hi) ^ (lm & 7)) * 8];
      }
#pragma unroll
      for (int m = 0; m < 4; ++m)
#pragma unroll
        for (int n = 0; n < 4; ++n)
          acc[m][n] = __builtin_amdgcn_mfma_f32_16x16x32_bf16(af[m], bfv[n], acc[m][n], 0, 0, 0);
    }
  }

  __syncthreads();
  uint8_t* ep = smem + wid * 10240;

  if constexpr (EPI == 0) {
    ushort(*E)[72] = (ushort(*)[72])ep;
    float bcol[4];
#pragma unroll
    for (int n = 0; n < 4; ++n) bcol[n] = bias[v * N + colBase + wc * 64 + n * 16 + lm];
#pragma unroll
    for (int m = 0; m < 4; ++m)
#pragma unroll
      for (int q = 0; q < 4; ++q) {
        int lr = m * 16 + hi * 4 + q;
#pragma unroll
        for (int n = 0; n < 4; ++n) E[lr][n * 16 + lm] = f2bf_bits(acc[m][n][q] + bcol[n]);
      }
    const int pr = lane >> 3, pc = lane & 7;
#pragma unroll
    for (int p = 0; p < 8; ++p) {
      int lr = p * 8 + pr;
      bf16x8 val = *(const bf16x8*)&E[lr][pc * 8];
      size_t grow = (size_t)v * PB + rowBase + wr * 64 + lr;
      int gcol = colBase + wc * 64 + pc * 8;
      *(bf16x8*)&outb[grow * N + gcol] = val;
    }
  } else {
    float(*F)[36] = (float(*)[36])ep;
    const int pr = lane >> 3, pc = lane & 7;
#pragma unroll
    for (int h2 = 0; h2 < 2; ++h2) {
#pragma unroll
      for (int m = 0; m < 4; ++m)
#pragma unroll
        for (int q = 0; q < 4; ++q) {
          int lr = m * 16 + hi * 4 + q;
#pragma unroll
          for (int n2 = 0; n2 < 2; ++n2) F[lr][n2 * 16 + lm] = acc[m][h2 * 2 + n2][q];
        }
#pragma unroll
      for (int p = 0; p < 8; ++p) {
        int lr = p * 8 + pr;
        f32x4 a4 = *(const f32x4*)&F[lr][pc * 4];
        int rowv = rowBase + wr * 64 + lr;
        int gcol = colBase + wc * 64 + h2 * 32 + pc * 4;
        f32x4 b4 = *(const f32x4*)&bias[v * N + gcol];
        int b_ = rowv >> 4, nn = rowv & 15;
        int zb = b_ % 13;
        int tt = b_ / 13;
        int wb = tt & 15, tt2 = tt >> 4;
        int hb = tt2 & 7, bb = tt2 >> 3;
        int h2v = (hb * 4 + (nn >> 2) + 2) & 31;
        int w2v = (wb * 4 + (nn & 3) + 2) & 63;
        size_t l = (size_t)(h2v * 64 + w2v) * 13 + zb;
        const float* xv = (v == 0) ? xi0 : (v == 1) ? xi1 : (v == 2) ? xi2 : xi3;
        f32x4 x4 = *(const f32x4*)(xv + ((size_t)bb * Ln + l) * 256 + gcol);
        f32x4 o4 = a4 + b4 + x4;
        *(f32x4*)(outf + (((size_t)v * Bn + bb) * Ln + l) * 256 + gcol) = o4;
      }
      if (h2 == 0) __builtin_amdgcn_s_waitcnt(0);
    }
  }
}

// ---------- fused MLP v9: 4-wave blocks (256 thr), 64 rows, each wave owns 16 rows and
// computes ALL 32 hid of the chunk for them; h never touches LDS — redistributed to the
// GEMM2 B-fragment layout via 8 ds_bpermute (sources share the lane's lm => same row).
// LDS = 32KB (xn slices then W1c@0/W2c@16K) -> 4 blocks/CU at VGPR<=128.
// GEMM1: mfma(w1f[t2], xnf) -> lane holds h[hid=t2*16+hi*4+q][row=lm].
// Exchange: requester (hi,lm) pulls P0/P1[t2=hi>>1] from lanes 2*(hi&1)*16+lm and +16,
//           yielding hf = h[row=lm][k=hi*8..+8]  (hid = (hi>>1)*16+(hi&1)*8+j = hi*8+j).
// GEMM2: mfma(w2f[ca], hf) -> lane holds out[col=ca*16+hi*4+q][row=lm] -> f32x4 RMW.
__global__ __launch_bounds__(256, 4) void mlp_fused9(
    const float* __restrict__ x2,            // d_out rows (LN input + residual)
    const __hip_bfloat16* __restrict__ W1T,  // [V][1024][256]
    const __hip_bfloat16* __restrict__ W2T,  // [V][256][1024]
    const float* __restrict__ b1, const float* __restrict__ b2,
    const float* __restrict__ g2, const float* __restrict__ bt2,
    float* __restrict__ outp) {
  const int v = blockIdx.z;
  const size_t gRow0 = (size_t)v * PB + (size_t)blockIdx.x * 64;

  __shared__ __align__(16) uint8_t smem[32768];
  uint8_t* W1c = smem;            // after xn phase
  uint8_t* W2c = smem + 16384;

  const int tid = threadIdx.x, wid = tid >> 6, lane = tid & 63;  // wid 0..3
  const int lm = lane & 15, hi = lane >> 4;
  const int rA = lane >> 3, lg = (lane & 7) ^ rA;

  // ---- Phase 0: LN2 rows wid*16..+16 -> xn slices @0 (slice = hi, granule ^(r&7)^slice) ----
  {
    f32x4 g4 = *(const f32x4*)(g2 + v * 256 + lane * 4);
    f32x4 b4l = *(const f32x4*)(bt2 + v * 256 + lane * 4);
    for (int i = 0; i < 16; ++i) {
      int r = wid * 16 + i;
      const float* xp = x2 + (gRow0 + r) * 256;
      float4 val = *(const float4*)(xp + lane * 4);
      float s = val.x + val.y + val.z + val.w;
      float sq = val.x * val.x + val.y * val.y + val.z * val.z + val.w * val.w;
#pragma unroll
      for (int o = 32; o; o >>= 1) {
        s += __shfl_xor(s, o);
        sq += __shfl_xor(sq, o);
      }
      float mean = s * (1.0f / 256.0f);
      float var = sq * (1.0f / 256.0f) - mean * mean;
      float rstd = rsqrtf(var + 1e-5f);
      ushort4 o4;
      o4.x = f2bf_bits((val.x - mean) * rstd * g4[0] + b4l[0]);
      o4.y = f2bf_bits((val.y - mean) * rstd * g4[1] + b4l[1]);
      o4.z = f2bf_bits((val.z - mean) * rstd * g4[2] + b4l[2]);
      o4.w = f2bf_bits((val.w - mean) * rstd * g4[3] + b4l[3]);
      int gph = ((lm >> 1) ^ (r & 7) ^ hi) & 7;
      *(ushort4*)(smem + hi * 8192 + r * 128 + gph * 16 + (lm & 1) * 8) = o4;
    }
  }
  __syncthreads();

  // ---- hoist xn fragments for this wave's rows (wid*16+lm), all K=256 -> 32 VGPR ----
  bf16x8 xnf[4][2];
  {
    int r = wid * 16 + lm;
#pragma unroll
    for (int t = 0; t < 4; ++t)
#pragma unroll
      for (int kk = 0; kk < 2; ++kk) {
        int gph = ((kk * 4 + hi) ^ (r & 7) ^ t) & 7;
        xnf[t][kk] = *(const bf16x8*)(smem + t * 8192 + r * 128 + gph * 16);
      }
  }

  // loop-invariant LDS read bases (swizzle independent of t2 / ca — derived)
  const int base_w1_k0 = lm * 128 + ((((0 * 4) + hi) ^ (lm & 7)) & 7) * 16;  // kk=0
  const int base_w1_k1 = lm * 128 + ((((1 * 4) + hi) ^ (lm & 7)) & 7) * 16;  // kk=1
  const int base_w2 = (lm >> 1) * 128 + ((((lm & 1) * 4 + hi) ^ ((lm >> 1) & 7)) & 7) * 16;
  // bpermute source byte-addresses (lane index * 4)
  const int addrA = (2 * (hi & 1) * 16 + lm) * 4;
  const int addrB = addrA + 64;

  f32x4 acc2[16];
#pragma unroll
  for (int ca = 0; ca < 16; ++ca) acc2[ca] = f32x4{0.f, 0.f, 0.f, 0.f};

  const bf16_t* W1v = (const bf16_t*)W1T + (size_t)v * 1024 * 256;
  const bf16_t* W2v = (const bf16_t*)W2T + (size_t)v * 256 * 1024;

  __syncthreads();  // all xnf hoists done before W staging overwrites the xn region

  for (int hc = 0; hc < 32; ++hc) {
    // ---- stage W1c [32 hid][256 k] as 4 slices [32][64] (16 instrs) ----
#pragma unroll
    for (int s = 0; s < 4; ++s) {
      int idx = wid * 4 + s;
      int t = idx >> 2, grp = idx & 3;
      gload_lds16(W1v + (size_t)(hc * 32 + grp * 8 + rA) * 256 + t * 64 + lg * 8,
                  W1c + t * 4096 + grp * 1024);
    }
    // ---- stage W2c [256 col][32 hid] col-pair packed [128][64] (16 instrs) ----
#pragma unroll
    for (int s = 0; s < 4; ++s) {
      int i = wid * 4 + s;
      int p = i * 8 + rA;
      int col = 2 * p + (lg >> 2);
      gload_lds16(W2v + (size_t)col * 1024 + hc * 32 + (lg & 3) * 8, W2c + i * 1024);
    }
    __syncthreads();  // stages resident (compiler drains vmcnt)

    // ---- GEMM1: both 16-hid tiles for this wave's 16 rows (16 MFMA) ----
    f32x4 acc1[2];
    acc1[0] = f32x4{0.f, 0.f, 0.f, 0.f};
    acc1[1] = f32x4{0.f, 0.f, 0.f, 0.f};
#pragma unroll
    for (int t2 = 0; t2 < 2; ++t2)
#pragma unroll
      for (int t = 0; t < 4; ++t)
#pragma unroll
        for (int kk = 0; kk < 2; ++kk) {
          const int off = t * 4096 + t2 * 2048 + (kk ? base_w1_k1 : base_w1_k0);
          bf16x8 w1f = *(const bf16x8*)(W1c + off);
          acc1[t2] = __builtin_amdgcn_mfma_f32_16x16x32_bf16(w1f, xnf[t][kk], acc1[t2], 0, 0, 0);
        }

    // ---- bias + GELU -> packed bf16 pairs P0/P1 per tile ----
    uint32_t P0[2], P1[2];
#pragma unroll
    for (int t2 = 0; t2 < 2; ++t2) {
      f32x4 b1v = *(const f32x4*)&b1[v * 1024 + hc * 32 + t2 * 16 + hi * 4];
      unsigned short e0 = f2bf_bits(gelu_f(acc1[t2][0] + b1v[0]));
      unsigned short e1 = f2bf_bits(gelu_f(acc1[t2][1] + b1v[1]));
      unsigned short e2 = f2bf_bits(gelu_f(acc1[t2][2] + b1v[2]));
      unsigned short e3 = f2bf_bits(gelu_f(acc1[t2][3] + b1v[3]));
      P0[t2] = (uint32_t)e0 | ((uint32_t)e1 << 16);
      P1[t2] = (uint32_t)e2 | ((uint32_t)e3 << 16);
    }

    // ---- in-register exchange: hf = h[row=lm][k=hi*8..+8] via 8 bpermutes ----
    uint32_t a0A = __builtin_amdgcn_ds_bpermute(addrA, (int)P0[0]);
    uint32_t a1A = __builtin_amdgcn_ds_bpermute(addrA, (int)P0[1]);
    uint32_t b0A = __builtin_amdgcn_ds_bpermute(addrA, (int)P1[0]);
    uint32_t b1A = __builtin_amdgcn_ds_bpermute(addrA, (int)P1[1]);
    uint32_t a0B = __builtin_amdgcn_ds_bpermute(addrB, (int)P0[0]);
    uint32_t a1B = __builtin_amdgcn_ds_bpermute(addrB, (int)P0[1]);
    uint32_t b0B = __builtin_amdgcn_ds_bpermute(addrB, (int)P1[0]);
    uint32_t b1B = __builtin_amdgcn_ds_bpermute(addrB, (int)P1[1]);
    uint4 hw4;
    hw4.x = (hi < 2) ? a0A : a1A;  // j0,j1
    hw4.y = (hi < 2) ? b0A : b1A;  // j2,j3
    hw4.z = (hi < 2) ? a0B : a1B;  // j4,j5
    hw4.w = (hi < 2) ? b0B : b1B;  // j6,j7
    bf16x8 hf = *reinterpret_cast<bf16x8*>(&hw4);

    // ---- GEMM2: 256 cols x own 16 rows, K=32 (16 MFMA) ----
#pragma unroll
    for (int ca = 0; ca < 16; ++ca) {
      bf16x8 w2f = *(const bf16x8*)(W2c + ca * 1024 + base_w2);
      acc2[ca] = __builtin_amdgcn_mfma_f32_16x16x32_bf16(w2f, hf, acc2[ca], 0, 0, 0);
    }
    __syncthreads();  // all reads of W1c/W2c done before next chunk's stage
  }

  // ---- epilogue: direct f32x4 RMW; out[row = wid*16+lm][col = ca*16+hi*4] ----
  {
    size_t orow = gRow0 + wid * 16 + lm;
    float* obase = outp + orow * 256;
#pragma unroll
    for (int ca = 0; ca < 16; ++ca) {
      int col = ca * 16 + hi * 4;
      f32x4 b4 = *(const f32x4*)&b2[v * 256 + col];
      float* o = obase + col;
      f32x4 cur = *(const f32x4*)o;
      f32x4 res = cur + acc2[ca] + b4;
      *(f32x4*)o = res;
    }
  }
}

extern "C" void kernel_launch(void* const* d_in, const int* in_sizes, int n_in,
                              void* d_out, int out_size, void* d_ws, size_t ws_size,
                              hipStream_t stream) {
  const float* x0 = (const float*)d_in[0];
  const float* x1 = (const float*)d_in[1];
  const float* x2i = (const float*)d_in[2];
  const float* x3 = (const float*)d_in[3];
  const float* qkv_w = (const float*)d_in[4];
  const float* qkv_b = (const float*)d_in[5];
  const float* proj_w = (const float*)d_in[6];
  const float* proj_b = (const float*)d_in[7];
  const float* n1g = (const float*)d_in[8];
  const float* n1b = (const float*)d_in[9];
  const float* n2g = (const float*)d_in[10];
  const float* n2b = (const float*)d_in[11];
  const float* fc1_w = (const float*)d_in[12];
  const float* fc1_b = (const float*)d_in[13];
  const float* fc2_w = (const float*)d_in[14];
  const float* fc2_b = (const float*)d_in[15];
  float* out = (float*)d_out;  // doubles as x2 buffer

  uint8_t* ws = (uint8_t*)d_ws;
  size_t off = 0;
  auto alloc = [&](size_t bytes) -> void* {
    void* p = ws + off;
    off += (bytes + 255) & ~(size_t)255;
    return p;
  };
  __hip_bfloat16* wqkvT = (__hip_bfloat16*)alloc((size_t)Vn * Cn * 768 * 2);
  __hip_bfloat16* wprojT = (__hip_bfloat16*)alloc((size_t)Vn * Cn * Cn * 2);
  __hip_bfloat16* wfc1T = (__hip_bfloat16*)alloc((size_t)Vn * Cn * HIDn * 2);
  __hip_bfloat16* wfc2T = (__hip_bfloat16*)alloc((size_t)Vn * HIDn * Cn * 2);
  __hip_bfloat16* xw = (__hip_bfloat16*)alloc((size_t)ROWS * Cn * 2);     // xw / ctx
  __hip_bfloat16* qkvb = (__hip_bfloat16*)alloc((size_t)ROWS * 768 * 2);  // qkv

  transpose_tile_kernel<<<dim3(768 / 64, 256 / 64, Vn), 256, 0, stream>>>(qkv_w, wqkvT, 256, 768);
  transpose_tile_kernel<<<dim3(256 / 64, 256 / 64, Vn), 256, 0, stream>>>(proj_w, wprojT, 256, 256);
  transpose_tile_kernel<<<dim3(1024 / 64, 256 / 64, Vn), 256, 0, stream>>>(fc1_w, wfc1T, 256, 1024);
  transpose_tile_kernel<<<dim3(256 / 64, 1024 / 64, Vn), 256, 0, stream>>>(fc2_w, wfc2T, 1024, 256);

  ln1_kernel<<<ROWS / 4, 256, 0, stream>>>(x0, x1, x2i, x3, n1g, n1b, xw);

  gemm4<0, 256, 768><<<dim3(416 * 6, 1, Vn), 256, 0, stream>>>(
      xw, wqkvT, qkv_b, qkvb, nullptr, nullptr, nullptr, nullptr, nullptr);

  attn_kernel<<<dim3(BWn, Vn), 256, 0, stream>>>(qkvb, xw /*ctx*/);

  gemm4<1, 256, 256><<<dim3(416 * 2, 1, Vn), 256, 0, stream>>>(
      xw /*ctx*/, wprojT, proj_b, nullptr, out /*x2*/, x0, x1, x2i, x3);

  mlp_fused9<<<dim3(PB / 64, 1, Vn), 256, 0, stream>>>(
      out /*x2*/, wfc1T, wfc2T, fc1_b, fc2_b, n2g, n2b, out);
}

// Round 17
// 850.942 us; speedup vs baseline: 1.1130x; 1.1130x over previous
//
#include <hip/hip_runtime.h>
#include <hip/hip_bf16.h>
#include <cstdint>
#include <cstddef>

#define DI __device__ __forceinline__

typedef __bf16 bf16_t;
typedef bf16_t bf16x8 __attribute__((ext_vector_type(8)));
typedef float f32x4 __attribute__((ext_vector_type(4)));

constexpr int Vn = 4, Bn = 2, Hn = 32, Wn = 64, Zn = 13, Cn = 256, HIDn = 1024;
constexpr int Ln = Hn * Wn * Zn;                 // 26624
constexpr int BWn = Bn * (Hn / 4) * (Wn / 4) * Zn; // 3328 windows (B_)
constexpr int PB = Bn * Ln;                      // 53248 rows per variable
constexpr int ROWS = Vn * PB;                    // 212992

// ---------- global -> LDS direct staging (16B per lane; LDS dest wave-uniform) ----------
DI void gload_lds16(const void* g, void* l) {
  __builtin_amdgcn_global_load_lds(
      (const __attribute__((address_space(1))) void*)g,
      (__attribute__((address_space(3))) void*)l, 16, 0, 0);
}

DI unsigned short f2bf_bits(float f) {
  __hip_bfloat16 h = __float2bfloat16(f);
  return *reinterpret_cast<unsigned short*>(&h);
}

DI float gelu_f(float x) {
  // sigmoid-form tanh-GELU with v_rcp_f32 (no IEEE divide)
  float u = x * x;
  float w = x * fmaf(0.044715f, u, 1.0f);
  float e = __expf(-1.5957691216057308f * w);
  return x * __builtin_amdgcn_rcpf(1.0f + e);
}

// ---------- tiled weight transpose: src [V][K][N] f32 -> dst [V][N][K] bf16 ----------
__global__ __launch_bounds__(256) void transpose_tile_kernel(
    const float* __restrict__ src, __hip_bfloat16* __restrict__ dst, int K, int N) {
  __shared__ float S[64][65];
  const int n0 = blockIdx.x * 64, k0 = blockIdx.y * 64, v = blockIdx.z;
  const int tc = threadIdx.x & 63, tr = threadIdx.x >> 6;  // tr 0..3
#pragma unroll
  for (int i = 0; i < 16; ++i) {
    int kk = tr + i * 4;
    S[kk][tc] = src[((size_t)v * K + k0 + kk) * N + n0 + tc];
  }
  __syncthreads();
#pragma unroll
  for (int i = 0; i < 16; ++i) {
    int nn = tr + i * 4;
    dst[((size_t)v * N + n0 + nn) * K + k0 + tc] = __float2bfloat16(S[tc][nn]);
  }
}

// ---------- LN1 fused with cyclic shift + window partition ----------
__global__ __launch_bounds__(256) void ln1_kernel(
    const float* __restrict__ x0, const float* __restrict__ x1,
    const float* __restrict__ x2i, const float* __restrict__ x3,
    const float* __restrict__ g_, const float* __restrict__ b_,
    __hip_bfloat16* __restrict__ xw) {
  int gw = blockIdx.x * 4 + (threadIdx.x >> 6);
  int lane = threadIdx.x & 63;
  int v = gw / PB;
  int rem = gw - v * PB;
  int bw = rem >> 4, nn = rem & 15;
  int zb = bw % 13;
  int t = bw / 13;
  int wb = t & 15, t2 = t >> 4;
  int hb = t2 & 7, b = t2 >> 3;
  int hs = (hb * 4 + (nn >> 2) + 30) & 31;   // (h - 2) mod 32
  int wsrc = (wb * 4 + (nn & 3) + 62) & 63;  // (w - 2) mod 64
  size_t l = (size_t)(hs * 64 + wsrc) * 13 + zb;
  const float* xv = (v == 0) ? x0 : (v == 1) ? x1 : (v == 2) ? x2i : x3;
  const float* xp = xv + ((size_t)b * Ln + l) * 256;
  float4 val = *(const float4*)(xp + lane * 4);
  float s = val.x + val.y + val.z + val.w;
  float sq = val.x * val.x + val.y * val.y + val.z * val.z + val.w * val.w;
#pragma unroll
  for (int o = 32; o; o >>= 1) {
    s += __shfl_xor(s, o);
    sq += __shfl_xor(sq, o);
  }
  float mean = s * (1.0f / 256.0f);
  float var = sq * (1.0f / 256.0f) - mean * mean;
  float rstd = rsqrtf(var + 1e-5f);
  const float* gg = g_ + v * 256 + lane * 4;
  const float* bb = b_ + v * 256 + lane * 4;
  ushort4 o4;
  o4.x = f2bf_bits((val.x - mean) * rstd * gg[0] + bb[0]);
  o4.y = f2bf_bits((val.y - mean) * rstd * gg[1] + bb[1]);
  o4.z = f2bf_bits((val.z - mean) * rstd * gg[2] + bb[2]);
  o4.w = f2bf_bits((val.w - mean) * rstd * gg[3] + bb[3]);
  *reinterpret_cast<ushort4*>(xw + (size_t)gw * 256 + lane * 4) = o4;
}

// ---------- windowed attention (verified) ----------
__global__ __launch_bounds__(256) void attn_kernel(
    const __hip_bfloat16* __restrict__ qkvp, __hip_bfloat16* __restrict__ ctx) {
  __shared__ float P[4][16][17];
  int b_ = blockIdx.x;
  int v = blockIdx.y;
  int wid = threadIdx.x >> 6, lane = threadIdx.x & 63;
  int lm = lane & 15, hi = lane >> 4;
  const bf16_t* base = (const bf16_t*)qkvp + (size_t)(v * BWn + b_) * 16 * 768;
  const float scale = 0.17677669529663687f;  // 32^-0.5
  f32x4 zero = {0.f, 0.f, 0.f, 0.f};
#pragma unroll
  for (int hh = 0; hh < 2; ++hh) {
    int h = wid + 4 * hh;
    bf16x8 qf = *(const bf16x8*)(base + (size_t)lm * 768 + h * 32 + hi * 8);
    bf16x8 kf = *(const bf16x8*)(base + (size_t)lm * 768 + 256 + h * 32 + hi * 8);
    f32x4 s = __builtin_amdgcn_mfma_f32_16x16x32_bf16(qf, kf, zero, 0, 0, 0);
    float p0[4];
#pragma unroll
    for (int q = 0; q < 4; ++q) {
      float val = s[q] * scale;
      float mx = val;
#pragma unroll
      for (int o = 8; o >= 1; o >>= 1) mx = fmaxf(mx, __shfl_xor(mx, o));
      float e = __expf(val - mx);
      float sum = e;
#pragma unroll
      for (int o = 8; o >= 1; o >>= 1) sum += __shfl_xor(sum, o);
      p0[q] = e * __builtin_amdgcn_rcpf(sum);
    }
#pragma unroll
    for (int q = 0; q < 4; ++q) P[wid][hi * 4 + q][lm] = p0[q];
    bf16x8 pa;
#pragma unroll
    for (int j = 0; j < 8; ++j) pa[j] = (bf16_t)0.f;
    if (hi < 2) {
#pragma unroll
      for (int j = 0; j < 8; ++j) pa[j] = (bf16_t)P[wid][lm][hi * 8 + j];
    }
#pragma unroll
    for (int dh = 0; dh < 2; ++dh) {
      bf16x8 vf;
#pragma unroll
      for (int j = 0; j < 8; ++j) vf[j] = (bf16_t)0.f;
      if (hi < 2) {
#pragma unroll
        for (int j = 0; j < 8; ++j)
          vf[j] = base[(size_t)(hi * 8 + j) * 768 + 512 + h * 32 + dh * 16 + lm];
      }
      f32x4 c = __builtin_amdgcn_mfma_f32_16x16x32_bf16(pa, vf, zero, 0, 0, 0);
#pragma unroll
      for (int q = 0; q < 4; ++q) {
        int n = hi * 4 + q;
        int d = dh * 16 + lm;
        int r = n * 4 + v;
        int vo = r >> 4, no = r & 15;
        ctx[((size_t)(vo * BWn + b_) * 16 + no) * 256 + h * 32 + d] = __float2bfloat16(c[q]);
      }
    }
  }
}

// ---------- GEMM v4 (verified): 128x128 tile, 4 waves, BK=64, 40KB LDS -> 3 blocks/CU ----------
// EPI: 0 = qkv (bias, bf16), 1 = proj (bias + window-reverse + roll + shortcut -> f32 x2)
template <int EPI, int K, int N>
__global__ __launch_bounds__(256, 3) void gemm4(
    const __hip_bfloat16* __restrict__ A, const __hip_bfloat16* __restrict__ WT,
    const float* __restrict__ bias, __hip_bfloat16* __restrict__ outb,
    float* __restrict__ outf, const float* __restrict__ xi0,
    const float* __restrict__ xi1, const float* __restrict__ xi2,
    const float* __restrict__ xi3) {
  constexpr int NT = K / 64;
  constexpr int NC = N / 128;
  const int v = blockIdx.z;
  const int x = blockIdx.x;
  const int xcd = x & 7;
  const int j = x >> 3;
  const int c = j % NC;
  const int r = xcd + 8 * (j / NC);
  const int rowBase = r * 128;
  const int colBase = c * 128;

  const bf16_t* Av = (const bf16_t*)A + ((size_t)v * PB + rowBase) * K;
  const bf16_t* Wv = (const bf16_t*)WT + ((size_t)v * N + colBase) * K;

  __shared__ __align__(16) uint8_t smem[40960];
  bf16_t(*As)[64] = (bf16_t(*)[64])smem;             // [128][64]
  bf16_t(*Bs)[64] = (bf16_t(*)[64])(smem + 16384);   // [128][64]

  const int tid = threadIdx.x, wid = tid >> 6, lane = tid & 63;
  const int wr = wid >> 1, wc = wid & 1;
  const int lm = lane & 15, hi = lane >> 4;
  const int rA = lane >> 3;
  const int lg = (lane & 7) ^ rA;

  f32x4 acc[4][4];
#pragma unroll
  for (int m = 0; m < 4; ++m)
#pragma unroll
    for (int n = 0; n < 4; ++n) acc[m][n] = f32x4{0.f, 0.f, 0.f, 0.f};

  for (int t = 0; t < NT; ++t) {
    if (t) __syncthreads();
#pragma unroll
    for (int g = 0; g < 4; ++g) {
      int grp = wid * 4 + g;
      gload_lds16(Av + (size_t)(grp * 8 + rA) * K + t * 64 + lg * 8, &As[grp * 8][0]);
    }
#pragma unroll
    for (int g = 0; g < 4; ++g) {
      int grp = wid * 4 + g;
      gload_lds16(Wv + (size_t)(grp * 8 + rA) * K + t * 64 + lg * 8, &Bs[grp * 8][0]);
    }
    __syncthreads();
#pragma unroll
    for (int kk = 0; kk < 2; ++kk) {
      bf16x8 af[4], bfv[4];
#pragma unroll
      for (int m = 0; m < 4; ++m) {
        const int rr = wr * 64 + m * 16 + lm;
        af[m] = *(const bf16x8*)&As[rr][((kk * 4 + hi) ^ (lm & 7)) * 8];
      }
#pragma unroll
      for (int n = 0; n < 4; ++n) {
        const int rr = wc * 64 + n * 16 + lm;
        bfv[n] = *(const bf16x8*)&Bs[rr][((kk * 4 + hi) ^ (lm & 7)) * 8];
      }
#pragma unroll
      for (int m = 0; m < 4; ++m)
#pragma unroll
        for (int n = 0; n < 4; ++n)
          acc[m][n] = __builtin_amdgcn_mfma_f32_16x16x32_bf16(af[m], bfv[n], acc[m][n], 0, 0, 0);
    }
  }

  __syncthreads();
  uint8_t* ep = smem + wid * 10240;

  if constexpr (EPI == 0) {
    ushort(*E)[72] = (ushort(*)[72])ep;
    float bcol[4];
#pragma unroll
    for (int n = 0; n < 4; ++n) bcol[n] = bias[v * N + colBase + wc * 64 + n * 16 + lm];
#pragma unroll
    for (int m = 0; m < 4; ++m)
#pragma unroll
      for (int q = 0; q < 4; ++q) {
        int lr = m * 16 + hi * 4 + q;
#pragma unroll
        for (int n = 0; n < 4; ++n) E[lr][n * 16 + lm] = f2bf_bits(acc[m][n][q] + bcol[n]);
      }
    const int pr = lane >> 3, pc = lane & 7;
#pragma unroll
    for (int p = 0; p < 8; ++p) {
      int lr = p * 8 + pr;
      bf16x8 val = *(const bf16x8*)&E[lr][pc * 8];
      size_t grow = (size_t)v * PB + rowBase + wr * 64 + lr;
      int gcol = colBase + wc * 64 + pc * 8;
      *(bf16x8*)&outb[grow * N + gcol] = val;
    }
  } else {
    float(*F)[36] = (float(*)[36])ep;
    const int pr = lane >> 3, pc = lane & 7;
#pragma unroll
    for (int h2 = 0; h2 < 2; ++h2) {
#pragma unroll
      for (int m = 0; m < 4; ++m)
#pragma unroll
        for (int q = 0; q < 4; ++q) {
          int lr = m * 16 + hi * 4 + q;
#pragma unroll
          for (int n2 = 0; n2 < 2; ++n2) F[lr][n2 * 16 + lm] = acc[m][h2 * 2 + n2][q];
        }
#pragma unroll
      for (int p = 0; p < 8; ++p) {
        int lr = p * 8 + pr;
        f32x4 a4 = *(const f32x4*)&F[lr][pc * 4];
        int rowv = rowBase + wr * 64 + lr;
        int gcol = colBase + wc * 64 + h2 * 32 + pc * 4;
        f32x4 b4 = *(const f32x4*)&bias[v * N + gcol];
        int b_ = rowv >> 4, nn = rowv & 15;
        int zb = b_ % 13;
        int tt = b_ / 13;
        int wb = tt & 15, tt2 = tt >> 4;
        int hb = tt2 & 7, bb = tt2 >> 3;
        int h2v = (hb * 4 + (nn >> 2) + 2) & 31;
        int w2v = (wb * 4 + (nn & 3) + 2) & 63;
        size_t l = (size_t)(h2v * 64 + w2v) * 13 + zb;
        const float* xv = (v == 0) ? xi0 : (v == 1) ? xi1 : (v == 2) ? xi2 : xi3;
        f32x4 x4 = *(const f32x4*)(xv + ((size_t)bb * Ln + l) * 256 + gcol);
        f32x4 o4 = a4 + b4 + x4;
        *(f32x4*)(outf + (((size_t)v * Bn + bb) * Ln + l) * 256 + gcol) = o4;
      }
      if (h2 == 0) __builtin_amdgcn_s_waitcnt(0);
    }
  }
}

// ---------- fused MLP v8 (champion): v5 + loop-invariant LDS offsets hoisted
// to registers + hc-loop unrolled x2 with compile-time buffer bases.
// 64 rows/block, hid-chunk 32, 68KB LDS -> 2 blocks/CU, 2 barriers/chunk, W dbuf.
__global__ __launch_bounds__(512, 4) void mlp_fused8(
    const float* __restrict__ x2,            // d_out rows (LN input + residual)
    const __hip_bfloat16* __restrict__ W1T,  // [V][1024][256]
    const __hip_bfloat16* __restrict__ W2T,  // [V][256][1024]
    const float* __restrict__ b1, const float* __restrict__ b2,
    const float* __restrict__ g2, const float* __restrict__ bt2,
    float* __restrict__ outp) {
  const int v = blockIdx.z;
  const size_t gRow0 = (size_t)v * PB + (size_t)blockIdx.x * 64;

  __shared__ __align__(16) uint8_t smem[69632];
  uint8_t* hb = smem + 65536;

  const int tid = threadIdx.x, wid = tid >> 6, lane = tid & 63;
  const int lm = lane & 15, hi = lane >> 4;
  const int wa = wid >> 2, wb = wid & 3;  // wa: hid/col half; wb: 16-row group
  const int rA = lane >> 3, lg = (lane & 7) ^ rA;

  // ---- Phase 0: LN2 rows wid*8..+8 -> xn slices @0 ----
  {
    f32x4 g4 = *(const f32x4*)(g2 + v * 256 + lane * 4);
    f32x4 b4l = *(const f32x4*)(bt2 + v * 256 + lane * 4);
    for (int i = 0; i < 8; ++i) {
      int r = wid * 8 + i;
      const float* xp = x2 + (gRow0 + r) * 256;
      float4 val = *(const float4*)(xp + lane * 4);
      float s = val.x + val.y + val.z + val.w;
      float sq = val.x * val.x + val.y * val.y + val.z * val.z + val.w * val.w;
#pragma unroll
      for (int o = 32; o; o >>= 1) {
        s += __shfl_xor(s, o);
        sq += __shfl_xor(sq, o);
      }
      float mean = s * (1.0f / 256.0f);
      float var = sq * (1.0f / 256.0f) - mean * mean;
      float rstd = rsqrtf(var + 1e-5f);
      ushort4 o4;
      o4.x = f2bf_bits((val.x - mean) * rstd * g4[0] + b4l[0]);
      o4.y = f2bf_bits((val.y - mean) * rstd * g4[1] + b4l[1]);
      o4.z = f2bf_bits((val.z - mean) * rstd * g4[2] + b4l[2]);
      o4.w = f2bf_bits((val.w - mean) * rstd * g4[3] + b4l[3]);
      int gph = ((lm >> 1) ^ (r & 7) ^ hi) & 7;
      *(ushort4*)(smem + hi * 8192 + r * 128 + gph * 16 + (lm & 1) * 8) = o4;
    }
  }
  __syncthreads();

  // ---- hoist xn fragments for this wave's rows -> 32 VGPR ----
  bf16x8 xnf[4][2];
  {
    int r = wb * 16 + lm;
#pragma unroll
    for (int t = 0; t < 4; ++t)
#pragma unroll
      for (int kk = 0; kk < 2; ++kk) {
        int gph = ((kk * 4 + hi) ^ (r & 7) ^ t) & 7;
        xnf[t][kk] = *(const bf16x8*)(smem + t * 8192 + r * 128 + gph * 16);
      }
  }

  // ---- precompute ALL loop-invariant LDS byte offsets (registers, reused 32x) ----
  int off_w1[8];  // GEMM1 read offsets within W1c
  {
    int hw = wa * 16 + lm;
#pragma unroll
    for (int t = 0; t < 4; ++t)
#pragma unroll
      for (int kk = 0; kk < 2; ++kk)
        off_w1[t * 2 + kk] = t * 4096 + hw * 128 + (((kk * 4 + hi) ^ (hw & 7)) & 7) * 16;
  }
  int off_w2[8];  // GEMM2 W2 read offsets within W2c
#pragma unroll
  for (int ca = 0; ca < 8; ++ca) {
    int col = wa * 128 + ca * 16 + lm;
    int p2 = col >> 1;
    off_w2[ca] = p2 * 128 + ((((col & 1) * 4 + hi) ^ (p2 & 7)) & 7) * 16;
  }
  int off_hf, off_hw;
  {
    int xr = wb * 16 + lm;
    int p = xr >> 1;
    off_hf = p * 128 + ((((xr & 1) * 4 + hi) ^ (p & 7)) & 7) * 16;
    int glog = (xr & 1) * 4 + wa * 2 + (hi >> 1);
    off_hw = p * 128 + ((glog ^ (p & 7)) & 7) * 16 + (hi & 1) * 8;
  }
  // staging per-lane global components (elements) + wave-uniform LDS dests
  int gsrc_w1[2], ldst_w1[2], gsrc_w2[2], ldst_w2[2];
#pragma unroll
  for (int s = 0; s < 2; ++s) {
    int idx = wid * 2 + s;
    int t = idx >> 2, grp = idx & 3;
    gsrc_w1[s] = (grp * 8 + rA) * 256 + t * 64 + lg * 8;
    ldst_w1[s] = t * 4096 + grp * 1024;
    int i = wid * 2 + s;
    int p = i * 8 + rA;
    int col = 2 * p + (lg >> 2);
    gsrc_w2[s] = col * 1024 + (lg & 3) * 8;
    ldst_w2[s] = i * 1024;
  }

  f32x4 acc2[8];
#pragma unroll
  for (int ca = 0; ca < 8; ++ca) acc2[ca] = f32x4{0.f, 0.f, 0.f, 0.f};

  const bf16_t* W1v = (const bf16_t*)W1T + (size_t)v * 1024 * 256;
  const bf16_t* W2v = (const bf16_t*)W2T + (size_t)v * 256 * 1024;

  auto stageW = [&](uint8_t* W1c, uint8_t* W2c, int hc) {
#pragma unroll
    for (int s = 0; s < 2; ++s)
      gload_lds16(W1v + (size_t)hc * 32 * 256 + gsrc_w1[s], W1c + ldst_w1[s]);
#pragma unroll
    for (int s = 0; s < 2; ++s)
      gload_lds16(W2v + hc * 32 + gsrc_w2[s], W2c + ldst_w2[s]);
  };

  // one chunk body; buffer bases are compile-time-selected by the caller
  auto chunk = [&](uint8_t* W1c, uint8_t* W2c, uint8_t* W1n, uint8_t* W2n,
                   int hc, bool stage_next) {
    if (stage_next) stageW(W1n, W2n, hc + 1);
    // GEMM1
    f32x4 acc1 = f32x4{0.f, 0.f, 0.f, 0.f};
#pragma unroll
    for (int j = 0; j < 8; ++j) {
      bf16x8 w1f = *(const bf16x8*)(W1c + off_w1[j]);
      acc1 = __builtin_amdgcn_mfma_f32_16x16x32_bf16(w1f, xnf[j >> 1][j & 1], acc1, 0, 0, 0);
    }
    // bias + GELU -> h
    {
      f32x4 b1v = *(const f32x4*)&b1[v * 1024 + hc * 32 + wa * 16 + hi * 4];
      ushort4 hp;
      hp.x = f2bf_bits(gelu_f(acc1[0] + b1v[0]));
      hp.y = f2bf_bits(gelu_f(acc1[1] + b1v[1]));
      hp.z = f2bf_bits(gelu_f(acc1[2] + b1v[2]));
      hp.w = f2bf_bits(gelu_f(acc1[3] + b1v[3]));
      *(ushort4*)(hb + off_hw) = hp;
    }
    __syncthreads();  // h visible; prefetch loads drained (hidden under GEMM1)
    // GEMM2
    {
      bf16x8 hf = *(const bf16x8*)(hb + off_hf);
#pragma unroll
      for (int ca = 0; ca < 8; ++ca) {
        bf16x8 w2f = *(const bf16x8*)(W2c + off_w2[ca]);
        acc2[ca] = __builtin_amdgcn_mfma_f32_16x16x32_bf16(w2f, hf, acc2[ca], 0, 0, 0);
      }
    }
    __syncthreads();  // reads of this buffer + h done before overwrite
  };

  stageW(smem + 32768, smem + 49152, 0);  // prologue into buf0
  __syncthreads();                        // buf0 resident; xnf hoists complete

  // unroll x2: even chunk uses buf0 {@32768,@49152}, odd uses buf1 {@0,@16384}
#pragma unroll 1
  for (int i = 0; i < 16; ++i) {
    chunk(smem + 32768, smem + 49152, smem, smem + 16384, 2 * i, true);
    chunk(smem, smem + 16384, smem + 32768, smem + 49152, 2 * i + 1, i != 15);
  }

  // ---- epilogue: direct f32x4 RMW ----
  {
    size_t orow = gRow0 + wb * 16 + lm;
    float* obase = outp + orow * 256;
#pragma unroll
    for (int ca = 0; ca < 8; ++ca) {
      int col = wa * 128 + ca * 16 + hi * 4;
      f32x4 b4 = *(const f32x4*)&b2[v * 256 + col];
      float* o = obase + col;
      f32x4 cur = *(const f32x4*)o;
      f32x4 res = cur + acc2[ca] + b4;
      *(f32x4*)o = res;
    }
  }
}

extern "C" void kernel_launch(void* const* d_in, const int* in_sizes, int n_in,
                              void* d_out, int out_size, void* d_ws, size_t ws_size,
                              hipStream_t stream) {
  const float* x0 = (const float*)d_in[0];
  const float* x1 = (const float*)d_in[1];
  const float* x2i = (const float*)d_in[2];
  const float* x3 = (const float*)d_in[3];
  const float* qkv_w = (const float*)d_in[4];
  const float* qkv_b = (const float*)d_in[5];
  const float* proj_w = (const float*)d_in[6];
  const float* proj_b = (const float*)d_in[7];
  const float* n1g = (const float*)d_in[8];
  const float* n1b = (const float*)d_in[9];
  const float* n2g = (const float*)d_in[10];
  const float* n2b = (const float*)d_in[11];
  const float* fc1_w = (const float*)d_in[12];
  const float* fc1_b = (const float*)d_in[13];
  const float* fc2_w = (const float*)d_in[14];
  const float* fc2_b = (const float*)d_in[15];
  float* out = (float*)d_out;  // doubles as x2 buffer

  uint8_t* ws = (uint8_t*)d_ws;
  size_t off = 0;
  auto alloc = [&](size_t bytes) -> void* {
    void* p = ws + off;
    off += (bytes + 255) & ~(size_t)255;
    return p;
  };
  __hip_bfloat16* wqkvT = (__hip_bfloat16*)alloc((size_t)Vn * Cn * 768 * 2);
  __hip_bfloat16* wprojT = (__hip_bfloat16*)alloc((size_t)Vn * Cn * Cn * 2);
  __hip_bfloat16* wfc1T = (__hip_bfloat16*)alloc((size_t)Vn * Cn * HIDn * 2);
  __hip_bfloat16* wfc2T = (__hip_bfloat16*)alloc((size_t)Vn * HIDn * Cn * 2);
  __hip_bfloat16* xw = (__hip_bfloat16*)alloc((size_t)ROWS * Cn * 2);     // xw / ctx
  __hip_bfloat16* qkvb = (__hip_bfloat16*)alloc((size_t)ROWS * 768 * 2);  // qkv

  transpose_tile_kernel<<<dim3(768 / 64, 256 / 64, Vn), 256, 0, stream>>>(qkv_w, wqkvT, 256, 768);
  transpose_tile_kernel<<<dim3(256 / 64, 256 / 64, Vn), 256, 0, stream>>>(proj_w, wprojT, 256, 256);
  transpose_tile_kernel<<<dim3(1024 / 64, 256 / 64, Vn), 256, 0, stream>>>(fc1_w, wfc1T, 256, 1024);
  transpose_tile_kernel<<<dim3(256 / 64, 1024 / 64, Vn), 256, 0, stream>>>(fc2_w, wfc2T, 1024, 256);

  ln1_kernel<<<ROWS / 4, 256, 0, stream>>>(x0, x1, x2i, x3, n1g, n1b, xw);

  gemm4<0, 256, 768><<<dim3(416 * 6, 1, Vn), 256, 0, stream>>>(
      xw, wqkvT, qkv_b, qkvb, nullptr, nullptr, nullptr, nullptr, nullptr);

  attn_kernel<<<dim3(BWn, Vn), 256, 0, stream>>>(qkvb, xw /*ctx*/);

  gemm4<1, 256, 256><<<dim3(416 * 2, 1, Vn), 256, 0, stream>>>(
      xw /*ctx*/, wprojT, proj_b, nullptr, out /*x2*/, x0, x1, x2i, x3);

  ln2_placeholder:;
  mlp_fused8<<<dim3(PB / 64, 1, Vn), 512, 0, stream>>>(
      out /*x2*/, wfc1T, wfc2T, fc1_b, fc2_b, n2g, n2b, out);
}